// Round 6
// baseline (114.254 us; speedup 1.0000x reference)
//
#include <hip/hip_runtime.h>
#include <math.h>

// z (16,64,64,64) f32 (b,c,h,w), codebook (1024,64) f32. Out: z_q + loss.
#define NB 16
#define NC 64
#define NH 64
#define NW 64
#define NE 1024
#define HW (NH * NW)              // 4096 = 1<<12
#define NTOT (NB * NC * NH * NW)  // 4194304
#define NPIX (NB * NH * NW)       // 65536 pixels (rows)

#define ROWS 128                  // pixels per block
#define NBLK (NPIX / ROWS)        // 512 blocks

typedef short bf16x8 __attribute__((ext_vector_type(8)));
typedef float f32x4  __attribute__((ext_vector_type(4)));

// XOR swizzle within a 128-byte row (A-tile LDS only).
__device__ __forceinline__ int swz(int row, int byteoff) {
    return (byteoff ^ ((row & 7) << 4));
}

// fp32 -> bf16 bits, round-to-nearest-even.
__device__ __forceinline__ unsigned short bf16bits(float f) {
    union { float f; unsigned u; } cv;
    cv.f = f;
    const unsigned u = cv.u;
    return (unsigned short)((u + 0x7FFFu + ((u >> 16) & 1u)) >> 16);
}

// ---------------- prep: bf16 codebook + (-0.5*||e||^2) into ws ----------------
// 4096 threads: row = gid>>2, quarter q = gid&2bits (16 channels each).
__global__ void vq_prep_kernel(const float* __restrict__ cb,
                               short* __restrict__ cbw,
                               float* __restrict__ ncbn) {
    const int gid = blockIdx.x * blockDim.x + threadIdx.x;  // 0..4095
    const int row = gid >> 2;
    const int q   = gid & 3;
    const float4* __restrict__ src = (const float4*)(cb + ((size_t)row << 6) + q * 16);
    float ssq = 0.f;
    bf16x8 pk0, pk1;
    {
        const float4 a = src[0], b = src[1];
        ssq += a.x * a.x + a.y * a.y + a.z * a.z + a.w * a.w
             + b.x * b.x + b.y * b.y + b.z * b.z + b.w * b.w;
        pk0[0] = (short)bf16bits(a.x); pk0[1] = (short)bf16bits(a.y);
        pk0[2] = (short)bf16bits(a.z); pk0[3] = (short)bf16bits(a.w);
        pk0[4] = (short)bf16bits(b.x); pk0[5] = (short)bf16bits(b.y);
        pk0[6] = (short)bf16bits(b.z); pk0[7] = (short)bf16bits(b.w);
    }
    {
        const float4 a = src[2], b = src[3];
        ssq += a.x * a.x + a.y * a.y + a.z * a.z + a.w * a.w
             + b.x * b.x + b.y * b.y + b.z * b.z + b.w * b.w;
        pk1[0] = (short)bf16bits(a.x); pk1[1] = (short)bf16bits(a.y);
        pk1[2] = (short)bf16bits(a.z); pk1[3] = (short)bf16bits(a.w);
        pk1[4] = (short)bf16bits(b.x); pk1[5] = (short)bf16bits(b.y);
        pk1[6] = (short)bf16bits(b.z); pk1[7] = (short)bf16bits(b.w);
    }
    bf16x8* dst = (bf16x8*)(cbw + ((size_t)row << 6) + q * 16);
    dst[0] = pk0;
    dst[1] = pk1;
    // reduce ssq across the 4 lanes of this row (consecutive lanes)
    ssq += __shfl_xor(ssq, 1, 64);
    ssq += __shfl_xor(ssq, 2, 64);
    if (q == 0) ncbn[row] = -0.5f * ssq;
}

// ---------------- main: barrier-free codebook sweep ----------------
// 512 blocks x 256 thr (4 waves, 32 rows/wave). A (z tile) in LDS; B frags
// straight from L2-resident bf16 codebook (no per-chunk staging/barriers).
// acc initialized to -0.5||e||^2 so score-max == argmin of distance.
__launch_bounds__(256, 2)
__global__ void vq_main_kernel(const float* __restrict__ z,
                               const short* __restrict__ cbw,
                               const float* __restrict__ ncbn,
                               const float* __restrict__ cb,
                               float* __restrict__ out,
                               float* __restrict__ loss) {
    __shared__ __align__(16) short zt[ROWS * 64];  // 16 KB, swizzled
    __shared__ float ncbn_s[NE];                   // 4 KB
    __shared__ int   rowi[ROWS];
    __shared__ float swsum[4];

    const int tid  = threadIdx.x;
    const int wave = tid >> 6;
    const int lane = tid & 63;
    const int bid  = blockIdx.x;

    // stage ncbn (1024 floats) via 256 x float4
    ((float4*)ncbn_s)[tid] = ((const float4*)ncbn)[tid];

    // ---- stage z tile (fp32 global -> bf16 LDS, swizzled) ----
    {
        const int r     = tid & 127;
        const int chalf = tid >> 7;
        const int P     = bid * ROWS + r;
        const int b     = P >> 12;
        const int rem   = P & 4095;
        const size_t zb = ((size_t)b << 18) + rem;
        #pragma unroll
        for (int q = 0; q < 4; ++q) {
            bf16x8 pk;
            #pragma unroll
            for (int jj = 0; jj < 8; ++jj) {
                const int c = chalf * 32 + q * 8 + jj;
                pk[jj] = (short)bf16bits(z[zb + ((size_t)c << 12)]);
            }
            const int boff = (chalf * 32 + q * 8) * 2;
            *(bf16x8*)((char*)zt + r * 128 + swz(r, boff)) = pk;
        }
    }
    __syncthreads();

    // ---- A fragments: lane l -> row (l&15), k = (l>>4)*8 + j ----
    bf16x8 af[2][2];
    #pragma unroll
    for (int m = 0; m < 2; ++m) {
        const int r = wave * 32 + m * 16 + (lane & 15);
        #pragma unroll
        for (int k0 = 0; k0 < 2; ++k0) {
            const int boff = k0 * 64 + (lane >> 4) * 16;
            af[m][k0] = *(const bf16x8*)((const char*)zt + r * 128 + swz(r, boff));
        }
    }

    float maxv[2][4];
    int   maxi[2][4];
    #pragma unroll
    for (int m = 0; m < 2; ++m)
        #pragma unroll
        for (int j = 0; j < 4; ++j) { maxv[m][j] = -INFINITY; maxi[m][j] = 0; }

    // ---- sweep all 1024 entries: 64 independent n-tiles, no barriers ----
    const short* __restrict__ bptr = cbw + ((lane >> 4) << 3);  // k-group byte 16*(lane>>4)
    #pragma unroll 4
    for (int nt = 0; nt < NE / 16; ++nt) {
        const int el = nt * 16 + (lane & 15);     // entry (= B col)
        const bf16x8 b0 = *(const bf16x8*)(bptr + el * 64);
        const bf16x8 b1 = *(const bf16x8*)(bptr + el * 64 + 32);
        const float  ncb = ncbn_s[el];
        #pragma unroll
        for (int m = 0; m < 2; ++m) {
            f32x4 acc = {ncb, ncb, ncb, ncb};
            acc = __builtin_amdgcn_mfma_f32_16x16x32_bf16(af[m][0], b0, acc, 0, 0, 0);
            acc = __builtin_amdgcn_mfma_f32_16x16x32_bf16(af[m][1], b1, acc, 0, 0, 0);
            #pragma unroll
            for (int j = 0; j < 4; ++j) {
                if (acc[j] > maxv[m][j]) { maxv[m][j] = acc[j]; maxi[m][j] = el; }
            }
        }
    }

    // ---- cross-lane argmax over the 16 cols per row ----
    // element (m, j, lane): row = wave*32 + m*16 + (lane>>4)*4 + j.
    #pragma unroll
    for (int m = 0; m < 2; ++m) {
        #pragma unroll
        for (int j = 0; j < 4; ++j) {
            float v = maxv[m][j];
            int   i = maxi[m][j];
            #pragma unroll
            for (int s = 1; s < 16; s <<= 1) {
                const float ov = __shfl_xor(v, s, 64);
                const int   oi = __shfl_xor(i, s, 64);
                if (ov > v || (ov == v && oi < i)) { v = ov; i = oi; }
            }
            if ((lane & 15) == 0) {
                const int r = wave * 32 + m * 16 + (lane >> 4) * 4 + j;
                rowi[r] = i;
            }
        }
    }
    __syncthreads();

    // ---- epilogue: gather fp32 codebook row, store out, loss ----
    float lsum = 0.f;
    {
        const int r     = tid & 127;
        const int chalf = tid >> 7;
        const int P     = bid * ROWS + r;
        const int b     = P >> 12;
        const int rem   = P & 4095;
        const size_t zb = ((size_t)b << 18) + rem;
        const int mi    = rowi[r];
        const float4* __restrict__ qrow = (const float4*)(cb + ((size_t)mi << 6));
        #pragma unroll
        for (int q = 0; q < 8; ++q) {
            const float4 q4 = qrow[chalf * 8 + q];
            const int c = chalf * 32 + q * 4;
            const float z0 = z[zb + ((size_t)(c + 0) << 12)];
            const float z1 = z[zb + ((size_t)(c + 1) << 12)];
            const float z2 = z[zb + ((size_t)(c + 2) << 12)];
            const float z3 = z[zb + ((size_t)(c + 3) << 12)];
            out[zb + ((size_t)(c + 0) << 12)] = q4.x;
            out[zb + ((size_t)(c + 1) << 12)] = q4.y;
            out[zb + ((size_t)(c + 2) << 12)] = q4.z;
            out[zb + ((size_t)(c + 3) << 12)] = q4.w;
            const float d0 = q4.x - z0, d1 = q4.y - z1;
            const float d2 = q4.z - z2, d3 = q4.w - z3;
            lsum += d0 * d0 + d1 * d1 + d2 * d2 + d3 * d3;
        }
    }

    #pragma unroll
    for (int off = 32; off > 0; off >>= 1)
        lsum += __shfl_xor(lsum, off, 64);
    if (lane == 0) swsum[wave] = lsum;
    __syncthreads();
    if (tid == 0) {
        const float s = (swsum[0] + swsum[1]) + (swsum[2] + swsum[3]);
        atomicAdd(loss, s * (1.25f / (float)NTOT));
    }
}

extern "C" void kernel_launch(void* const* d_in, const int* in_sizes, int n_in,
                              void* d_out, int out_size, void* d_ws, size_t ws_size,
                              hipStream_t stream) {
    const float* z  = (const float*)d_in[0];
    const float* cb = (const float*)d_in[1];
    float* out  = (float*)d_out;
    float* loss = out + (out_size - 1);

    short* cbw  = (short*)d_ws;                 // [1024][64] bf16 (128 KB)
    float* ncbn = (float*)(cbw + NE * NC);      // [1024] f32 (4 KB)

    (void)hipMemsetAsync(loss, 0, sizeof(float), stream);
    vq_prep_kernel<<<dim3(16), dim3(256), 0, stream>>>(cb, cbw, ncbn);
    vq_main_kernel<<<dim3(NBLK), dim3(256), 0, stream>>>(z, cbw, ncbn, cb, out, loss);
}